// Round 6
// baseline (1815.873 us; speedup 1.0000x reference)
//
#include <hip/hip_runtime.h>

// GRUModel: B=4096, H=512, V=512, T=31, D_IN=14
// d_out = [probs: 4096*31*512 f32][hidden: 4096*31*512 f32]
#define NTH 15872   // 31*512

typedef __bf16 bf16x8 __attribute__((ext_vector_type(8)));
typedef float  f32x4  __attribute__((ext_vector_type(4)));

__device__ __forceinline__ unsigned short f2bf(float f) {
    unsigned u = __float_as_uint(f);
    u = u + 0x7fffu + ((u >> 16) & 1u);
    return (unsigned short)(u >> 16);
}
__device__ __forceinline__ float sigm(float x)  { return 1.f / (1.f + __expf(-x)); }
__device__ __forceinline__ float tanhf_(float x){ return 2.f / (1.f + __expf(-2.f * x)) - 1.f; }

// R1-proven LDS tile layout (64B rows, K=32 bf16): chunk ^= (r>>1)&3.
__device__ __forceinline__ int lds_off(int r, int kb) {
    return r * 64 + ((kb ^ ((r >> 1) & 3)) << 4);
}
__device__ __forceinline__ int4 ldg16(const char* g0, int stride, int kbyte, int c) {
    int r = c >> 2, kb = c & 3;
    return *(const int4*)(g0 + (size_t)r * stride + kbyte + kb * 16);
}
__device__ __forceinline__ void sts16(char* lds, int c, int4 v) {
    int r = c >> 2, kb = c & 3;
    *(int4*)(lds + lds_off(r, kb)) = v;
}
__device__ __forceinline__ bf16x8 ldsfrag(const char* lds, int row, int hi) {
    return *(const bf16x8*)(lds + lds_off(row, hi));
}
// load 8 f32 (stride in floats), round to bf16, pack to one 16B chunk
__device__ __forceinline__ int4 ldg16_f32(const float* g0, int stride, int koff, int c) {
    int r = c >> 2, kb = c & 3;
    const float4* p = (const float4*)(g0 + (size_t)r * stride + koff + kb * 8);
    float4 a = p[0], b = p[1];
    union { unsigned short us[8]; int4 v; } u;
    u.us[0]=f2bf(a.x); u.us[1]=f2bf(a.y); u.us[2]=f2bf(a.z); u.us[3]=f2bf(a.w);
    u.us[4]=f2bf(b.x); u.us[5]=f2bf(b.y); u.us[6]=f2bf(b.z); u.us[7]=f2bf(b.w);
    return u.v;
}

// ---------------------------------------------------------------- converts
__global__ void k_f32_to_bf16(const float* __restrict__ in,
                              unsigned short* __restrict__ out, int n4) {
    int i = blockIdx.x * 256 + threadIdx.x;
    if (i < n4) {
        float4 v = ((const float4*)in)[i];
        ushort4 o;
        o.x = f2bf(v.x); o.y = f2bf(v.y); o.z = f2bf(v.z); o.w = f2bf(v.w);
        ((ushort4*)out)[i] = o;
    }
}

// ---------------------------------------------------------------- x = inputs @ W_in.T + b_in  -> bf16
__global__ void k_linear_in(const float* __restrict__ inp,   // [4096,14]
                            const float* __restrict__ W,     // [512,14]
                            const float* __restrict__ bias,  // [512]
                            unsigned short* __restrict__ xb) // [4096,512] bf16
{
    int idx = blockIdx.x * 256 + threadIdx.x;   // b*512 + j
    int b = idx >> 9, j = idx & 511;
    const float* ir = inp + (size_t)b * 14;
    const float* wr = W + (size_t)j * 14;
    float acc = bias[j];
#pragma unroll
    for (int k = 0; k < 14; ++k) acc += ir[k] * wr[k];
    xb[idx] = f2bf(acc);
}

// ---------------------------------------------------------------- giT = (x @ W_ih.T + b_ih)^T  [1536,4096] f32
// R1-proven loop; epilogue writes TRANSPOSED as float4 (m-contiguous).
__global__ __launch_bounds__(256) void k_gemm_gi(
    const unsigned short* __restrict__ A,   // [4096,512] bf16
    const unsigned short* __restrict__ W,   // [1536,512] bf16
    const float* __restrict__ bias,         // [1536]
    float* __restrict__ C)                  // [1536,4096]  (transposed!)
{
    __shared__ __align__(16) char lA[128 * 64];
    __shared__ __align__(16) char lB[64 * 64];
    const int tid = threadIdx.x, lane = tid & 63, wid = tid >> 6;
    const int wm = wid >> 1, wn = wid & 1, hi = lane >> 4, c16 = lane & 15;
    const int m0 = blockIdx.x * 128, n0 = blockIdx.y * 64;
    const char* ga = (const char*)(A + (size_t)m0 * 512);
    const char* gb = (const char*)(W + (size_t)n0 * 512);
    f32x4 acc[4][2] = {};
    int4 ra0 = ldg16(ga, 1024, 0, tid);
    int4 ra1 = ldg16(ga, 1024, 0, tid + 256);
    int4 rb0 = ldg16(gb, 1024, 0, tid);
    for (int kt = 0; kt < 16; ++kt) {
        if (kt) __syncthreads();
        sts16(lA, tid, ra0); sts16(lA, tid + 256, ra1); sts16(lB, tid, rb0);
        __syncthreads();
        if (kt < 15) {
            int kb = (kt + 1) * 64;
            ra0 = ldg16(ga, 1024, kb, tid);
            ra1 = ldg16(ga, 1024, kb, tid + 256);
            rb0 = ldg16(gb, 1024, kb, tid);
        }
        bf16x8 af[4];
#pragma unroll
        for (int i = 0; i < 4; ++i) af[i] = ldsfrag(lA, wm * 64 + i * 16 + c16, hi);
#pragma unroll
        for (int j = 0; j < 2; ++j) {
            bf16x8 bfr = ldsfrag(lB, wn * 32 + j * 16 + c16, hi);
#pragma unroll
            for (int i = 0; i < 4; ++i)
                acc[i][j] = __builtin_amdgcn_mfma_f32_16x16x32_bf16(af[i], bfr, acc[i][j], 0, 0, 0);
        }
    }
#pragma unroll
    for (int i = 0; i < 4; ++i) {
        int m = m0 + wm * 64 + i * 16 + hi * 4;
#pragma unroll
        for (int j = 0; j < 2; ++j) {
            int n = n0 + wn * 32 + j * 16 + c16;
            float bj = bias[n];
            float4 v = make_float4(acc[i][j][0] + bj, acc[i][j][1] + bj,
                                   acc[i][j][2] + bj, acc[i][j][3] + bj);
            *(float4*)(C + (size_t)n * 4096 + m) = v;
        }
    }
}

// ---------------------------------------------------------------- persistent GRU recurrence
// Grid 256 = 16m x 16n blocks, 512 thr (8 waves, 4wm x 2wn). Block: 256 rows x 32 cols/gate.
// W panel (3x32 rows x 512k bf16 = 98 KB) resident in LDS for all 31 steps.
// gi (48 f32) + h (16 f32) live in registers for all 31 steps.
// Cross-block h exchange: hx ping-pong [2][16 nb][4096 m][32 col] bf16 — each
// block writes only its own 256-row x 64-B region slice (cache-line disjoint).
// Grid barrier: monotonic counter, device-scope acq-rel atomics + fences (G16).
// LDS 128 KB forces 1 block/CU -> all 256 blocks co-resident (barrier safe).
__global__ __launch_bounds__(512, 2) void k_gru_persist(
    const unsigned short* __restrict__ Whh,   // [1536,512] bf16
    const float* __restrict__ giT,            // [1536,4096] f32 (b_ih folded)
    const float* __restrict__ bhh,            // [1536]
    float* __restrict__ hidden,               // [4096,15872] f32 (d_out region)
    unsigned short* __restrict__ hx,          // [2][16][4096][32] bf16
    unsigned int* __restrict__ bar)           // monotonic arrival counter
{
    __shared__ __align__(16) char lW[98304];       // [16 kt][96 r][64 B], lds_off per slab
    __shared__ __align__(16) char lA[2][16384];    // [256 r][64 B], lds_off
    const int tid = threadIdx.x, lane = tid & 63, wid = tid >> 6;
    const int wm = wid >> 1, wn = wid & 1, hi = lane >> 4, c16 = lane & 15;
    const int mb = blockIdx.x >> 4, nb = blockIdx.x & 15;
    const int m0 = mb * 256, n0 = nb * 32;

    // ---- stage W panel once: rows r = g*32 + rl (gate g, local col rl), all K
    for (int s = 0; s < 12; ++s) {
        int c = tid + 512 * s;                 // [0, 6144) chunks of 16 B
        int kt = c / 384, rem = c - kt * 384;
        int r = rem >> 2, kb = rem & 3;
        int g = r >> 5, rl = r & 31;
        const int4 v = *(const int4*)(Whh + ((size_t)(g * 512 + n0 + rl)) * 512 + kt * 32 + kb * 8);
        *(int4*)(lW + kt * 6144 + lds_off(r, kb)) = v;
    }
    // ---- per-thread gi fragments + biases, held across all steps
    const int ncol = n0 + wn * 16 + c16;       // h feature / gate-local column
    float4 gir[3][4];
#pragma unroll
    for (int g = 0; g < 3; ++g)
#pragma unroll
        for (int mf = 0; mf < 4; ++mf) {
            int m = m0 + wm * 64 + mf * 16 + hi * 4;
            gir[g][mf] = *(const float4*)(giT + (size_t)(g * 512 + ncol) * 4096 + m);
        }
    const float br = bhh[ncol], bz = bhh[512 + ncol], bn_ = bhh[1024 + ncol];
    float hreg[4][4] = {{0.f}};
    __syncthreads();

    for (int t = 0; t < 31; ++t) {
        f32x4 acc[3][4] = {};
        if (t > 0) {
            const unsigned short* hin = hx + (size_t)((t + 1) & 1) * 2097152;
            const char* pa[2]; int la[2];
#pragma unroll
            for (int s = 0; s < 2; ++s) {
                int c = tid + 512 * s, r = c >> 2, kb = c & 3;
                // feature block of chunk kb at k-step kt is exactly region kt:
                // src = hin + kt*131072 + (m0+r)*32 + kb*8  (elements)
                pa[s] = (const char*)(hin + (size_t)(m0 + r) * 32 + kb * 8);
                la[s] = lds_off(r, kb);
            }
            int4 ra[2];
#pragma unroll
            for (int s = 0; s < 2; ++s) ra[s] = *(const int4*)pa[s];   // kt=0 region
            int cur = 0;
            for (int kt = 0; kt < 16; ++kt) {
                __syncthreads();
#pragma unroll
                for (int s = 0; s < 2; ++s) *(int4*)(lA[cur] + la[s]) = ra[s];
                __syncthreads();
                if (kt < 15) {
#pragma unroll
                    for (int s = 0; s < 2; ++s)
                        ra[s] = *(const int4*)(pa[s] + (size_t)(kt + 1) * 262144);
                }
                bf16x8 af[4];
#pragma unroll
                for (int mf = 0; mf < 4; ++mf)
                    af[mf] = *(const bf16x8*)(lA[cur] + lds_off(wm * 64 + mf * 16 + c16, hi));
#pragma unroll
                for (int g = 0; g < 3; ++g) {
                    bf16x8 bfr = *(const bf16x8*)(lW + kt * 6144 + lds_off(g * 32 + wn * 16 + c16, hi));
#pragma unroll
                    for (int mf = 0; mf < 4; ++mf)
                        acc[g][mf] = __builtin_amdgcn_mfma_f32_16x16x32_bf16(af[mf], bfr, acc[g][mf], 0, 0, 0);
                }
                cur ^= 1;
            }
        }
        // ---- epilogue: gate math, h in registers
        unsigned short* hox = hx + (size_t)(t & 1) * 2097152 + (size_t)nb * 131072;
#pragma unroll
        for (int mf = 0; mf < 4; ++mf) {
#pragma unroll
            for (int q = 0; q < 4; ++q) {
                int m = m0 + wm * 64 + mf * 16 + hi * 4 + q;
                float pr = gir[0][mf][q] + acc[0][mf][q] + br;
                float pz = gir[1][mf][q] + acc[1][mf][q] + bz;
                float r  = sigm(pr);
                float z  = sigm(pz);
                float nn = tanhf_(gir[2][mf][q] + r * (acc[2][mf][q] + bn_));
                float hn = (1.f - z) * nn + z * hreg[mf][q];
                hreg[mf][q] = hn;
                hidden[(size_t)m * NTH + (size_t)t * 512 + ncol] = hn;
                hox[(size_t)m * 32 + (ncol & 31)] = f2bf(hn);
            }
        }
        // ---- grid barrier (skip after last step)
        if (t < 30) {
            __syncthreads();
            if (tid == 0) {
                __threadfence();   // release h writes (device scope)
                __hip_atomic_fetch_add(bar, 1u, __ATOMIC_ACQ_REL, __HIP_MEMORY_SCOPE_AGENT);
                const unsigned target = 256u * (unsigned)(t + 1);
                unsigned spins = 0;
                while (__hip_atomic_load(bar, __ATOMIC_ACQUIRE, __HIP_MEMORY_SCOPE_AGENT) < target
                       && ++spins < 0x4000000u) {
                    __builtin_amdgcn_s_sleep(2);
                }
                __threadfence();   // acquire side
            }
            __syncthreads();
        }
    }
}

// ---------------------------------------------------------------- projection + softmax (R4-proven shape)
// BM=64, BN=512 (full V), BK=32, 256 thr = 4 waves in 2x2; wave tile 32x256.
template<bool BF16A>
__global__ __launch_bounds__(256) void k_proj(
    const void* __restrict__ Aptr,          // f32 [126976,512] (astr elems) when BF16A=false
    int astr,
    const unsigned short* __restrict__ Wo,  // [512,512] bf16
    const float* __restrict__ bo,
    float* __restrict__ out)                // [126976,512]
{
    __shared__ __align__(16) char lA[64 * 64];
    __shared__ __align__(16) char lB[512 * 64];
    __shared__ float red[2][2][32];
    const int tid = threadIdx.x, lane = tid & 63, wid = tid >> 6;
    const int wm = wid >> 1, wn = wid & 1, hi = lane >> 4, c16 = lane & 15;
    const int m0 = blockIdx.x * 64;
    const char*  gab = (const char*)Aptr  + (size_t)m0 * astr * 2;
    const float* gaf = (const float*)Aptr + (size_t)m0 * astr;
    const char*  gb  = (const char*)Wo;
    f32x4 acc[2][16] = {};
    int4 ra = BF16A ? ldg16(gab, astr * 2, 0, tid) : ldg16_f32(gaf, astr, 0, tid);
    int4 rb[8];
#pragma unroll
    for (int s = 0; s < 8; ++s) rb[s] = ldg16(gb, 1024, 0, tid + 256 * s);
    for (int kt = 0; kt < 16; ++kt) {
        if (kt) __syncthreads();
        sts16(lA, tid, ra);
#pragma unroll
        for (int s = 0; s < 8; ++s) sts16(lB, tid + 256 * s, rb[s]);
        __syncthreads();
        if (kt < 15) {
            ra = BF16A ? ldg16(gab, astr * 2, (kt + 1) * 64, tid)
                       : ldg16_f32(gaf, astr, (kt + 1) * 32, tid);
#pragma unroll
            for (int s = 0; s < 8; ++s) rb[s] = ldg16(gb, 1024, (kt + 1) * 64, tid + 256 * s);
        }
        bf16x8 af[2];
#pragma unroll
        for (int mf = 0; mf < 2; ++mf)
            af[mf] = ldsfrag(lA, wm * 32 + mf * 16 + c16, hi);
#pragma unroll
        for (int nf = 0; nf < 16; ++nf) {
            bf16x8 bfr = ldsfrag(lB, wn * 256 + nf * 16 + c16, hi);
#pragma unroll
            for (int mf = 0; mf < 2; ++mf)
                acc[mf][nf] = __builtin_amdgcn_mfma_f32_16x16x32_bf16(af[mf], bfr, acc[mf][nf], 0, 0, 0);
        }
    }
#pragma unroll
    for (int nf = 0; nf < 16; ++nf) {
        float bj = bo[wn * 256 + nf * 16 + c16];
#pragma unroll
        for (int mf = 0; mf < 2; ++mf)
#pragma unroll
            for (int q = 0; q < 4; ++q)
                acc[mf][nf][q] = __expf(acc[mf][nf][q] + bj);
    }
#pragma unroll
    for (int mf = 0; mf < 2; ++mf)
#pragma unroll
        for (int q = 0; q < 4; ++q) {
            float s = 0.f;
#pragma unroll
            for (int nf = 0; nf < 16; ++nf) s += acc[mf][nf][q];
            s += __shfl_xor(s, 1); s += __shfl_xor(s, 2);
            s += __shfl_xor(s, 4); s += __shfl_xor(s, 8);
            if (c16 == 0) red[wm][wn][mf * 16 + hi * 4 + q] = s;
        }
    __syncthreads();
#pragma unroll
    for (int mf = 0; mf < 2; ++mf)
#pragma unroll
        for (int q = 0; q < 4; ++q) {
            int rl = mf * 16 + hi * 4 + q;
            float inv = 1.f / (red[wm][0][rl] + red[wm][1][rl]);
            int m = m0 + wm * 32 + rl;
            float* orow = out + (size_t)m * 512 + wn * 256 + c16;
#pragma unroll
            for (int nf = 0; nf < 16; ++nf) orow[nf * 16] = acc[mf][nf][q] * inv;
        }
}

// ---------------------------------------------------------------- launch
extern "C" void kernel_launch(void* const* d_in, const int* in_sizes, int n_in,
                              void* d_out, int out_size, void* d_ws, size_t ws_size,
                              hipStream_t stream) {
    const float* inputs = (const float*)d_in[0];
    const float* W_in   = (const float*)d_in[1];
    const float* b_in   = (const float*)d_in[2];
    const float* W_ih   = (const float*)d_in[3];
    const float* b_ih   = (const float*)d_in[4];
    const float* W_hh   = (const float*)d_in[5];
    const float* b_hh   = (const float*)d_in[6];
    const float* W_out  = (const float*)d_in[7];
    const float* b_out  = (const float*)d_in[8];

    float* out    = (float*)d_out;
    float* hidden = out + (size_t)126976 * 512;

    char* ws = (char*)d_ws;
    unsigned short* wih_b  = (unsigned short*)(ws);                 // 1.5 MB
    unsigned short* whh_b  = (unsigned short*)(ws + 1572864);       // 1.5 MB
    unsigned short* wout_b = (unsigned short*)(ws + 3145728);       // 0.5 MB
    unsigned short* x_b    = (unsigned short*)(ws + 3670016);       // 4 MB (dead after k_gemm_gi)
    unsigned int*   bar    = (unsigned int*)(ws + 3670016);         // overlaps dead x_b
    float*          giT    = (float*)(ws + 7864320);                // 25.2 MB [1536,4096]
    unsigned short* hx     = (unsigned short*)(ws + 33030144);      // 8 MB [2][16][4096][32]
    // total footprint 41418752 B == R1-proven workspace floor

    k_f32_to_bf16<<<768, 256, 0, stream>>>(W_ih, wih_b, 196608);
    k_f32_to_bf16<<<768, 256, 0, stream>>>(W_hh, whh_b, 196608);
    k_f32_to_bf16<<<256, 256, 0, stream>>>(W_out, wout_b, 65536);
    k_linear_in<<<8192, 256, 0, stream>>>(inputs, W_in, b_in, x_b);
    k_gemm_gi<<<dim3(32, 24), 256, 0, stream>>>(x_b, wih_b, b_ih, giT);

    hipMemsetAsync(bar, 0, 128, stream);   // x_b is dead now; deterministic barrier init
    k_gru_persist<<<256, 512, 0, stream>>>(whh_b, giT, b_hh, hidden, hx, bar);

    k_proj<false><<<1984, 256, 0, stream>>>(hidden, 512, wout_b, b_out, out);
}